// Round 4
// baseline (2120.249 us; speedup 1.0000x reference)
//
#include <hip/hip_runtime.h>
#include <hip/hip_bf16.h>

#define DF 128        // feature dim
#define WPB 4         // waves (edges/nodes) per 256-thread block

// sum across the 8 lanes of a capsule group (lanes l..l|7)
__device__ __forceinline__ float cap_sum(float v) {
    v += __shfl_xor(v, 1);
    v += __shfl_xor(v, 2);
    v += __shfl_xor(v, 4);
    return v;
}

// load this lane's 2 features of node `node` from x (fp32 or bf16 per flag)
__device__ __forceinline__ float2 load_x2(const void* __restrict__ xraw, int fp32,
                                          int node, int lane) {
    size_t off = (size_t)node * DF + (size_t)lane * 2;
    if (fp32) {
        return *reinterpret_cast<const float2*>((const float*)xraw + off);
    } else {
        const __hip_bfloat162 v =
            *reinterpret_cast<const __hip_bfloat162*>((const __hip_bfloat16*)xraw + off);
        return make_float2(__bfloat162float(v.x), __bfloat162float(v.y));
    }
}

// Detector: flags[0]=x_is_fp32 (confirmed fp32 on this harness by R1->R2 NaN
// transition, kept for robustness), flags[1]=edge_index_is_int64.
__global__ void k_detect(const unsigned int* __restrict__ xw,
                         const unsigned int* __restrict__ ew,
                         int* __restrict__ flags) {
    __shared__ int s_nan, s_zero;
    int tid = threadIdx.x;
    if (tid == 0) { s_nan = 0; s_zero = 0; }
    __syncthreads();
    int cnt_nan = 0;
    for (int i = tid; i < 16384; i += 256) {
        unsigned int lo = xw[i] & 0xFFFFu;
        if ((lo & 0x7F80u) == 0x7F80u) cnt_nan++;   // impossible in normal bf16 data
    }
    int cnt_zero = 0;
    for (int i = tid; i < 1024; i += 256) {
        if (ew[2 * i + 1] == 0u) cnt_zero++;        // int64 high words are all zero
    }
    atomicAdd(&s_nan, cnt_nan);
    atomicAdd(&s_zero, cnt_zero);
    __syncthreads();
    if (tid == 0) {
        flags[0] = (s_nan > 0) ? 1 : 0;
        flags[1] = (s_zero > 512) ? 1 : 0;
    }
}

// Kernel 1: u = per-capsule l2norm(x) (fp32, in d_out); unew = 0.
__global__ void k_init(const void* __restrict__ xraw,
                       float* __restrict__ u, float* __restrict__ unew,
                       const int* __restrict__ flags, int n_nodes) {
    int wid  = (blockIdx.x * blockDim.x + threadIdx.x) >> 6;
    int lane = threadIdx.x & 63;
    if (wid >= n_nodes) return;
    float2 v = load_x2(xraw, flags[0], wid, lane);
    float ss = cap_sum(v.x * v.x + v.y * v.y);
    float scale = 1.0f / fmaxf(sqrtf(ss), 1e-12f);
    size_t off = (size_t)wid * DF + (size_t)lane * 2;
    *reinterpret_cast<float2*>(u + off)    = make_float2(v.x * scale, v.y * scale);
    *reinterpret_cast<float2*>(unew + off) = make_float2(0.0f, 0.0f);
}

// Kernel 2: per edge e: z = l2norm_cap(x[src]); p_c = <z, u[trg]>_c;
// softmax over caps; atomic-accumulate z*w into unew[trg]. One wave/edge.
__global__ void k_edge(const int* __restrict__ ei, const void* __restrict__ xraw,
                       const float* __restrict__ u,
                       float* __restrict__ unew, const int* __restrict__ flags,
                       int n_edges, int n_nodes) {
    int e    = (blockIdx.x * blockDim.x + threadIdx.x) >> 6;
    int lane = threadIdx.x & 63;
    if (e >= n_edges) return;
    int i64 = flags[1];
    size_t si = i64 ? (size_t)2 * e             : (size_t)e;
    size_t ti = i64 ? (size_t)2 * (n_edges + e) : (size_t)(n_edges + e);
    int s = ei[si];
    int t = ei[ti];
    if ((unsigned)s >= (unsigned)n_nodes || (unsigned)t >= (unsigned)n_nodes) return;
    // z = per-capsule-normalized x[s]
    float2 xs = load_x2(xraw, flags[0], s, lane);
    float ssz = cap_sum(xs.x * xs.x + xs.y * xs.y);
    float scz = 1.0f / fmaxf(sqrtf(ssz), 1e-12f);
    float zx = xs.x * scz, zy = xs.y * scz;
    // u[t] (fp32, lives in d_out)
    size_t toff = (size_t)t * DF + (size_t)lane * 2;
    const float2 ut = *reinterpret_cast<const float2*>(u + toff);
    // per-capsule agreement (lanes 8k..8k+7 -> capsule k)
    float p = cap_sum(zx * ut.x + zy * ut.y);
    // softmax across the 8 capsules: butterflies over lane-xor {8,16,32}
    float m = p;
    m = fmaxf(m, __shfl_xor(m, 8));
    m = fmaxf(m, __shfl_xor(m, 16));
    m = fmaxf(m, __shfl_xor(m, 32));
    float ex = __expf(p - m);
    float sd = ex;
    sd += __shfl_xor(sd, 8);
    sd += __shfl_xor(sd, 16);
    sd += __shfl_xor(sd, 32);
    float w = ex / sd;
    float* dst = unew + toff;
    atomicAdd(dst,     zx * w);   // safe atomic (CAS fallback ok on any memory)
    atomicAdd(dst + 1, zy * w);
}

// Kernel 3: u = l2norm_cap(unew + l2norm_cap(x)) (fp32 -> d_out); reset unew.
__global__ void k_norm(const float* __restrict__ unew_in, const void* __restrict__ xraw,
                       float* __restrict__ u, float* __restrict__ unew_rst,
                       const int* __restrict__ flags, int n_nodes) {
    int wid  = (blockIdx.x * blockDim.x + threadIdx.x) >> 6;
    int lane = threadIdx.x & 63;
    if (wid >= n_nodes) return;
    size_t off = (size_t)wid * DF + (size_t)lane * 2;
    float2 a = *reinterpret_cast<const float2*>(unew_in + off);
    float2 xv = load_x2(xraw, flags[0], wid, lane);
    float ssx = cap_sum(xv.x * xv.x + xv.y * xv.y);
    float scx = 1.0f / fmaxf(sqrtf(ssx), 1e-12f);
    float vx = a.x + xv.x * scx, vy = a.y + xv.y * scx;
    float ss = cap_sum(vx * vx + vy * vy);
    float scale = 1.0f / fmaxf(sqrtf(ss), 1e-12f);
    *reinterpret_cast<float2*>(u + off)        = make_float2(vx * scale, vy * scale);
    *reinterpret_cast<float2*>(unew_rst + off) = make_float2(0.0f, 0.0f);
}

extern "C" void kernel_launch(void* const* d_in, const int* in_sizes, int n_in,
                              void* d_out, int out_size, void* d_ws, size_t ws_size,
                              hipStream_t stream) {
    const void* x  = d_in[0];
    const int*  ei = (const int*)d_in[1];
    const int n_nodes = in_sizes[0] / DF;        // 50000
    const int n_edges = in_sizes[1] / 2;         // 800000

    // ws layout: unew fp32 [n_nodes*DF] | flags int[2]   (~25.6 MB total)
    float* unew = (float*)d_ws;
    const size_t NC = (size_t)n_nodes * DF;
    int* flags = (int*)((float*)d_ws + NC);

    float* u = (float*)d_out;                    // u lives in d_out as fp32

    const int tpb = 64 * WPB;                    // 256
    const int nb_nodes = (n_nodes + WPB - 1) / WPB;
    const int nb_edges = (n_edges + WPB - 1) / WPB;

    k_detect<<<1, 256, 0, stream>>>((const unsigned int*)x, (const unsigned int*)ei, flags);
    k_init<<<nb_nodes, tpb, 0, stream>>>(x, u, unew, flags, n_nodes);
    for (int it = 0; it < 3; ++it) {
        k_edge<<<nb_edges, tpb, 0, stream>>>(ei, x, u, unew, flags, n_edges, n_nodes);
        k_norm<<<nb_nodes, tpb, 0, stream>>>(unew, x, u, unew, flags, n_nodes);
    }
}

// Round 5
// 589.279 us; speedup vs baseline: 3.5980x; 3.5980x over previous
//
#include <hip/hip_runtime.h>
#include <hip/hip_bf16.h>

#define DF 128        // feature dim
#define WPB 4         // waves per 256-thread block

// sum across the 8 lanes of a capsule group (lanes l..l|7)
__device__ __forceinline__ float cap_sum(float v) {
    v += __shfl_xor(v, 1);
    v += __shfl_xor(v, 2);
    v += __shfl_xor(v, 4);
    return v;
}

// load this lane's 2 features of node `node` from x (fp32 or bf16 per flag)
__device__ __forceinline__ float2 load_x2(const void* __restrict__ xraw, int fp32,
                                          int node, int lane) {
    size_t off = (size_t)node * DF + (size_t)lane * 2;
    if (fp32) {
        return *reinterpret_cast<const float2*>((const float*)xraw + off);
    } else {
        const __hip_bfloat162 v =
            *reinterpret_cast<const __hip_bfloat162*>((const __hip_bfloat16*)xraw + off);
        return make_float2(__bfloat162float(v.x), __bfloat162float(v.y));
    }
}

// flags[0]=x_is_fp32, flags[1]=edge_index_is_int64
__global__ void k_detect(const unsigned int* __restrict__ xw,
                         const unsigned int* __restrict__ ew,
                         int* __restrict__ flags) {
    __shared__ int s_nan, s_zero;
    int tid = threadIdx.x;
    if (tid == 0) { s_nan = 0; s_zero = 0; }
    __syncthreads();
    int cnt_nan = 0;
    for (int i = tid; i < 16384; i += 256) {
        unsigned int lo = xw[i] & 0xFFFFu;
        if ((lo & 0x7F80u) == 0x7F80u) cnt_nan++;
    }
    int cnt_zero = 0;
    for (int i = tid; i < 1024; i += 256) {
        if (ew[2 * i + 1] == 0u) cnt_zero++;
    }
    atomicAdd(&s_nan, cnt_nan);
    atomicAdd(&s_zero, cnt_zero);
    __syncthreads();
    if (tid == 0) {
        flags[0] = (s_nan > 0) ? 1 : 0;
        flags[1] = (s_zero > 512) ? 1 : 0;
    }
}

__device__ __forceinline__ int2 edge_st(const int* __restrict__ ei, int i64,
                                        int e, int n_edges) {
    size_t si = i64 ? (size_t)2 * e             : (size_t)e;
    size_t ti = i64 ? (size_t)2 * (n_edges + e) : (size_t)(n_edges + e);
    return make_int2(ei[si], ei[ti]);
}

// ---------- CSR build (once per launch) ----------
__global__ void k_zero(int* __restrict__ cnt, int n) {
    int i = blockIdx.x * blockDim.x + threadIdx.x;
    if (i < n) cnt[i] = 0;
}

__global__ void k_hist(const int* __restrict__ ei, int* __restrict__ cnt,
                       const int* __restrict__ flags, int n_edges, int n_nodes) {
    int e = blockIdx.x * blockDim.x + threadIdx.x;
    if (e >= n_edges) return;
    int2 st = edge_st(ei, flags[1], e, n_edges);
    if ((unsigned)st.y < (unsigned)n_nodes && (unsigned)st.x < (unsigned)n_nodes)
        atomicAdd(&cnt[st.y], 1);
}

// per-block sums of cnt
__global__ void k_scan_a(const int* __restrict__ cnt, int* __restrict__ bsum, int n) {
    __shared__ int sh[256];
    int i = blockIdx.x * 256 + threadIdx.x;
    sh[threadIdx.x] = (i < n) ? cnt[i] : 0;
    __syncthreads();
    for (int off = 128; off > 0; off >>= 1) {
        if (threadIdx.x < off) sh[threadIdx.x] += sh[threadIdx.x + off];
        __syncthreads();
    }
    if (threadIdx.x == 0) bsum[blockIdx.x] = sh[0];
}

// exclusive scan of block sums (nb <= 256), single block
__global__ void k_scan_b(const int* __restrict__ bsum, int* __restrict__ bpre, int nb) {
    __shared__ int sh[256];
    int tid = threadIdx.x;
    int v = (tid < nb) ? bsum[tid] : 0;
    sh[tid] = v;
    __syncthreads();
    for (int off = 1; off < 256; off <<= 1) {
        int a = (tid >= off) ? sh[tid - off] : 0;
        __syncthreads();
        sh[tid] += a;
        __syncthreads();
    }
    if (tid < nb) bpre[tid] = sh[tid] - v;   // exclusive
}

// row_ptr[i] = bpre[b] + local exclusive; cursor[i] = row_ptr[i]
__global__ void k_scan_c(const int* __restrict__ cnt, const int* __restrict__ bpre,
                         int* __restrict__ row_ptr, int* __restrict__ cursor,
                         int n, int n_edges) {
    __shared__ int sh[256];
    int tid = threadIdx.x;
    int i = blockIdx.x * 256 + tid;
    int v = (i < n) ? cnt[i] : 0;
    sh[tid] = v;
    __syncthreads();
    for (int off = 1; off < 256; off <<= 1) {
        int a = (tid >= off) ? sh[tid - off] : 0;
        __syncthreads();
        sh[tid] += a;
        __syncthreads();
    }
    if (i < n) {
        int r = bpre[blockIdx.x] + sh[tid] - v;
        row_ptr[i] = r;
        cursor[i]  = r;
    }
    if (i == 0) row_ptr[n] = n_edges;   // valid-edge count == n_edges here
}

// elist[pos] = src, grouped by target
__global__ void k_scatter(const int* __restrict__ ei, int* __restrict__ cursor,
                          int* __restrict__ elist, const int* __restrict__ flags,
                          int n_edges, int n_nodes) {
    int e = blockIdx.x * blockDim.x + threadIdx.x;
    if (e >= n_edges) return;
    int2 st = edge_st(ei, flags[1], e, n_edges);
    if ((unsigned)st.y < (unsigned)n_nodes && (unsigned)st.x < (unsigned)n_nodes) {
        int pos = atomicAdd(&cursor[st.y], 1);
        elist[pos] = st.x;
    }
}

// ---------- fused routing iteration: one wave per target node ----------
// u_new[t] = l2norm_cap( sum_{s in N(t)} softmax_c(<z_s, u_old[t]>) * z_s + xc[t] )
// where z_s = l2norm_cap(x[s]).  FIRST: u_old[t] := xc[t] (computed from x).
template <bool FIRST>
__global__ void k_route(const int* __restrict__ row_ptr, const int* __restrict__ elist,
                        const void* __restrict__ xraw, const float* __restrict__ u_old,
                        float* __restrict__ u_new, const int* __restrict__ flags,
                        int n_nodes) {
    int t    = (blockIdx.x * blockDim.x + threadIdx.x) >> 6;
    int lane = threadIdx.x & 63;
    if (t >= n_nodes) return;
    const int fp32 = flags[0];

    // xc[t] (residual term), and u_old[t]
    float2 xt = load_x2(xraw, fp32, t, lane);
    float ssx = cap_sum(xt.x * xt.x + xt.y * xt.y);
    float scx = 1.0f / fmaxf(sqrtf(ssx), 1e-12f);
    float xcx = xt.x * scx, xcy = xt.y * scx;
    float utx, uty;
    if (FIRST) {
        utx = xcx; uty = xcy;
    } else {
        const float2 uo = *reinterpret_cast<const float2*>(
            u_old + (size_t)t * DF + (size_t)lane * 2);
        utx = uo.x; uty = uo.y;
    }

    int beg = __builtin_amdgcn_readfirstlane(row_ptr[t]);
    int end = __builtin_amdgcn_readfirstlane(row_ptr[t + 1]);

    float ax = 0.0f, ay = 0.0f;
    if (beg < end) {
        int s = __builtin_amdgcn_readfirstlane(elist[beg]);
        float2 xs = load_x2(xraw, fp32, s, lane);
        for (int i = beg; i < end; ++i) {
            // prefetch next edge's gather before the shuffle chain
            float2 xn;
            int sn = 0;
            if (i + 1 < end) {
                sn = __builtin_amdgcn_readfirstlane(elist[i + 1]);
                xn = load_x2(xraw, fp32, sn, lane);
            }
            // z = l2norm_cap(x[s])
            float ssz = cap_sum(xs.x * xs.x + xs.y * xs.y);
            float rz = 1.0f / fmaxf(sqrtf(ssz), 1e-12f);
            float zx = xs.x * rz, zy = xs.y * rz;
            // per-capsule agreement
            float p = cap_sum(zx * utx + zy * uty);
            // softmax over the 8 capsules (butterflies across cap groups)
            float m = p;
            m = fmaxf(m, __shfl_xor(m, 8));
            m = fmaxf(m, __shfl_xor(m, 16));
            m = fmaxf(m, __shfl_xor(m, 32));
            float ex = __expf(p - m);
            float sd = ex;
            sd += __shfl_xor(sd, 8);
            sd += __shfl_xor(sd, 16);
            sd += __shfl_xor(sd, 32);
            float w = ex / sd;
            ax = fmaf(zx, w, ax);
            ay = fmaf(zy, w, ay);
            xs = xn;
        }
    }
    // residual + renorm
    float vx = ax + xcx, vy = ay + xcy;
    float ss = cap_sum(vx * vx + vy * vy);
    float sc = 1.0f / fmaxf(sqrtf(ss), 1e-12f);
    *reinterpret_cast<float2*>(u_new + (size_t)t * DF + (size_t)lane * 2) =
        make_float2(vx * sc, vy * sc);
}

// ---------- R4 fallback kernels (used only if ws is too small for CSR) ----------
__global__ void k_init_fb(const void* __restrict__ xraw, float* __restrict__ u,
                          float* __restrict__ unew, const int* __restrict__ flags,
                          int n_nodes) {
    int wid  = (blockIdx.x * blockDim.x + threadIdx.x) >> 6;
    int lane = threadIdx.x & 63;
    if (wid >= n_nodes) return;
    float2 v = load_x2(xraw, flags[0], wid, lane);
    float ss = cap_sum(v.x * v.x + v.y * v.y);
    float scale = 1.0f / fmaxf(sqrtf(ss), 1e-12f);
    size_t off = (size_t)wid * DF + (size_t)lane * 2;
    *reinterpret_cast<float2*>(u + off)    = make_float2(v.x * scale, v.y * scale);
    *reinterpret_cast<float2*>(unew + off) = make_float2(0.0f, 0.0f);
}

__global__ void k_edge_fb(const int* __restrict__ ei, const void* __restrict__ xraw,
                          const float* __restrict__ u, float* __restrict__ unew,
                          const int* __restrict__ flags, int n_edges, int n_nodes) {
    int e    = (blockIdx.x * blockDim.x + threadIdx.x) >> 6;
    int lane = threadIdx.x & 63;
    if (e >= n_edges) return;
    int2 st = edge_st(ei, flags[1], e, n_edges);
    if ((unsigned)st.x >= (unsigned)n_nodes || (unsigned)st.y >= (unsigned)n_nodes) return;
    float2 xs = load_x2(xraw, flags[0], st.x, lane);
    float ssz = cap_sum(xs.x * xs.x + xs.y * xs.y);
    float scz = 1.0f / fmaxf(sqrtf(ssz), 1e-12f);
    float zx = xs.x * scz, zy = xs.y * scz;
    size_t toff = (size_t)st.y * DF + (size_t)lane * 2;
    const float2 ut = *reinterpret_cast<const float2*>(u + toff);
    float p = cap_sum(zx * ut.x + zy * ut.y);
    float m = p;
    m = fmaxf(m, __shfl_xor(m, 8));
    m = fmaxf(m, __shfl_xor(m, 16));
    m = fmaxf(m, __shfl_xor(m, 32));
    float ex = __expf(p - m);
    float sd = ex;
    sd += __shfl_xor(sd, 8);
    sd += __shfl_xor(sd, 16);
    sd += __shfl_xor(sd, 32);
    float w = ex / sd;
    atomicAdd(unew + toff,     zx * w);
    atomicAdd(unew + toff + 1, zy * w);
}

__global__ void k_norm_fb(const float* __restrict__ unew_in, const void* __restrict__ xraw,
                          float* __restrict__ u, float* __restrict__ unew_rst,
                          const int* __restrict__ flags, int n_nodes) {
    int wid  = (blockIdx.x * blockDim.x + threadIdx.x) >> 6;
    int lane = threadIdx.x & 63;
    if (wid >= n_nodes) return;
    size_t off = (size_t)wid * DF + (size_t)lane * 2;
    float2 a = *reinterpret_cast<const float2*>(unew_in + off);
    float2 xv = load_x2(xraw, flags[0], wid, lane);
    float ssx = cap_sum(xv.x * xv.x + xv.y * xv.y);
    float scx = 1.0f / fmaxf(sqrtf(ssx), 1e-12f);
    float vx = a.x + xv.x * scx, vy = a.y + xv.y * scx;
    float ss = cap_sum(vx * vx + vy * vy);
    float scale = 1.0f / fmaxf(sqrtf(ss), 1e-12f);
    *reinterpret_cast<float2*>(u + off)        = make_float2(vx * scale, vy * scale);
    *reinterpret_cast<float2*>(unew_rst + off) = make_float2(0.0f, 0.0f);
}

extern "C" void kernel_launch(void* const* d_in, const int* in_sizes, int n_in,
                              void* d_out, int out_size, void* d_ws, size_t ws_size,
                              hipStream_t stream) {
    const void* x  = d_in[0];
    const int*  ei = (const int*)d_in[1];
    const int n_nodes = in_sizes[0] / DF;        // 50000
    const int n_edges = in_sizes[1] / 2;         // 800000

    const size_t NC = (size_t)n_nodes * DF;      // 6.4M floats
    float* u_out = (float*)d_out;                // fp32 output / u buffer

    // ws layout (CSR path): u_buf f32[NC] | row_ptr[n+1] | cursor[n] |
    //                       elist[E] | bsum[256] | bpre[256] | flags[2]
    float* u_ws    = (float*)d_ws;
    int*   row_ptr = (int*)(u_ws + NC);
    int*   cursor  = row_ptr + (n_nodes + 1);
    int*   elist   = cursor + n_nodes;
    int*   bsum    = elist + n_edges;
    int*   bpre    = bsum + 256;
    int*   flags   = bpre + 256;
    size_t need = (size_t)(flags + 2 - (int*)d_ws) * 4;

    const int tpb = 64 * WPB;                    // 256
    const int nb_nodes = (n_nodes + WPB - 1) / WPB;
    const int nb_flat_nodes = (n_nodes + 255) / 256;   // 196
    const int nb_flat_edges = (n_edges + 255) / 256;   // 3125

    if (ws_size >= need) {
        k_detect<<<1, 256, 0, stream>>>((const unsigned int*)x, (const unsigned int*)ei, flags);
        // CSR build: cnt lives in `cursor` until scan_c rewrites it to row starts
        k_zero<<<nb_flat_nodes, 256, 0, stream>>>(cursor, n_nodes);
        k_hist<<<nb_flat_edges, 256, 0, stream>>>(ei, cursor, flags, n_edges, n_nodes);
        k_scan_a<<<nb_flat_nodes, 256, 0, stream>>>(cursor, bsum, n_nodes);
        k_scan_b<<<1, 256, 0, stream>>>(bsum, bpre, nb_flat_nodes);
        k_scan_c<<<nb_flat_nodes, 256, 0, stream>>>(cursor, bpre, row_ptr, cursor,
                                                    n_nodes, n_edges);
        k_scatter<<<nb_flat_edges, 256, 0, stream>>>(ei, cursor, elist, flags,
                                                     n_edges, n_nodes);
        // routing: iter1 x->d_out, iter2 d_out->ws_u, iter3 ws_u->d_out
        k_route<true ><<<nb_nodes, tpb, 0, stream>>>(row_ptr, elist, x, nullptr, u_out,
                                                     flags, n_nodes);
        k_route<false><<<nb_nodes, tpb, 0, stream>>>(row_ptr, elist, x, u_out, u_ws,
                                                     flags, n_nodes);
        k_route<false><<<nb_nodes, tpb, 0, stream>>>(row_ptr, elist, x, u_ws, u_out,
                                                     flags, n_nodes);
    } else {
        // R4 fallback: unew f32[NC] | flags
        float* unew = (float*)d_ws;
        int* flags_fb = (int*)((float*)d_ws + NC);
        k_detect<<<1, 256, 0, stream>>>((const unsigned int*)x, (const unsigned int*)ei, flags_fb);
        k_init_fb<<<nb_nodes, tpb, 0, stream>>>(x, u_out, unew, flags_fb, n_nodes);
        for (int it = 0; it < 3; ++it) {
            k_edge_fb<<<(n_edges + WPB - 1) / WPB, tpb, 0, stream>>>(
                ei, x, u_out, unew, flags_fb, n_edges, n_nodes);
            k_norm_fb<<<nb_nodes, tpb, 0, stream>>>(unew, x, u_out, unew, flags_fb, n_nodes);
        }
    }
}

// Round 6
// 347.012 us; speedup vs baseline: 6.1100x; 1.6982x over previous
//
#include <hip/hip_runtime.h>
#include <hip/hip_bf16.h>

#define DF  128       // feature dim
#define DPC 16        // dims per capsule (8 caps)
#define WPB 4         // waves per 256-thread block

// sum across the 8 lanes of a capsule group (lanes l..l|7) — used by k_xc only
__device__ __forceinline__ float cap_sum(float v) {
    v += __shfl_xor(v, 1);
    v += __shfl_xor(v, 2);
    v += __shfl_xor(v, 4);
    return v;
}

// load this lane's 2 features of node `node` from x (fp32 or bf16 per flag)
__device__ __forceinline__ float2 load_x2(const void* __restrict__ xraw, int fp32,
                                          int node, int lane) {
    size_t off = (size_t)node * DF + (size_t)lane * 2;
    if (fp32) {
        return *reinterpret_cast<const float2*>((const float*)xraw + off);
    } else {
        const __hip_bfloat162 v =
            *reinterpret_cast<const __hip_bfloat162*>((const __hip_bfloat16*)xraw + off);
        return make_float2(__bfloat162float(v.x), __bfloat162float(v.y));
    }
}

// flags[0]=x_is_fp32, flags[1]=edge_index_is_int64
__global__ void k_detect(const unsigned int* __restrict__ xw,
                         const unsigned int* __restrict__ ew,
                         int* __restrict__ flags) {
    __shared__ int s_nan, s_zero;
    int tid = threadIdx.x;
    if (tid == 0) { s_nan = 0; s_zero = 0; }
    __syncthreads();
    int cnt_nan = 0;
    for (int i = tid; i < 16384; i += 256) {
        unsigned int lo = xw[i] & 0xFFFFu;
        if ((lo & 0x7F80u) == 0x7F80u) cnt_nan++;
    }
    int cnt_zero = 0;
    for (int i = tid; i < 1024; i += 256) {
        if (ew[2 * i + 1] == 0u) cnt_zero++;
    }
    atomicAdd(&s_nan, cnt_nan);
    atomicAdd(&s_zero, cnt_zero);
    __syncthreads();
    if (tid == 0) {
        flags[0] = (s_nan > 0) ? 1 : 0;
        flags[1] = (s_zero > 512) ? 1 : 0;
    }
}

__device__ __forceinline__ int2 edge_st(const int* __restrict__ ei, int i64,
                                        int e, int n_edges) {
    size_t si = i64 ? (size_t)2 * e             : (size_t)e;
    size_t ti = i64 ? (size_t)2 * (n_edges + e) : (size_t)(n_edges + e);
    return make_int2(ei[si], ei[ti]);
}

// xc = per-capsule l2norm(x), fp32, written once to ws. One wave per node.
__global__ void k_xc(const void* __restrict__ xraw, float* __restrict__ xc,
                     const int* __restrict__ flags, int n_nodes) {
    int wid  = (blockIdx.x * blockDim.x + threadIdx.x) >> 6;
    int lane = threadIdx.x & 63;
    if (wid >= n_nodes) return;
    float2 v = load_x2(xraw, flags[0], wid, lane);
    float ss = cap_sum(v.x * v.x + v.y * v.y);
    float scale = 1.0f / fmaxf(sqrtf(ss), 1e-12f);
    *reinterpret_cast<float2*>(xc + (size_t)wid * DF + (size_t)lane * 2) =
        make_float2(v.x * scale, v.y * scale);
}

// ---------- CSR build (once per launch) ----------
__global__ void k_zero(int* __restrict__ cnt, int n) {
    int i = blockIdx.x * blockDim.x + threadIdx.x;
    if (i < n) cnt[i] = 0;
}

__global__ void k_hist(const int* __restrict__ ei, int* __restrict__ cnt,
                       const int* __restrict__ flags, int n_edges, int n_nodes) {
    int e = blockIdx.x * blockDim.x + threadIdx.x;
    if (e >= n_edges) return;
    int2 st = edge_st(ei, flags[1], e, n_edges);
    if ((unsigned)st.y < (unsigned)n_nodes && (unsigned)st.x < (unsigned)n_nodes)
        atomicAdd(&cnt[st.y], 1);
}

__global__ void k_scan_a(const int* __restrict__ cnt, int* __restrict__ bsum, int n) {
    __shared__ int sh[256];
    int i = blockIdx.x * 256 + threadIdx.x;
    sh[threadIdx.x] = (i < n) ? cnt[i] : 0;
    __syncthreads();
    for (int off = 128; off > 0; off >>= 1) {
        if (threadIdx.x < off) sh[threadIdx.x] += sh[threadIdx.x + off];
        __syncthreads();
    }
    if (threadIdx.x == 0) bsum[blockIdx.x] = sh[0];
}

__global__ void k_scan_b(const int* __restrict__ bsum, int* __restrict__ bpre, int nb) {
    __shared__ int sh[256];
    int tid = threadIdx.x;
    int v = (tid < nb) ? bsum[tid] : 0;
    sh[tid] = v;
    __syncthreads();
    for (int off = 1; off < 256; off <<= 1) {
        int a = (tid >= off) ? sh[tid - off] : 0;
        __syncthreads();
        sh[tid] += a;
        __syncthreads();
    }
    if (tid < nb) bpre[tid] = sh[tid] - v;   // exclusive
}

__global__ void k_scan_c(const int* __restrict__ cnt, const int* __restrict__ bpre,
                         int* __restrict__ row_ptr, int* __restrict__ cursor,
                         int n, int n_edges) {
    __shared__ int sh[256];
    int tid = threadIdx.x;
    int i = blockIdx.x * 256 + tid;
    int v = (i < n) ? cnt[i] : 0;
    sh[tid] = v;
    __syncthreads();
    for (int off = 1; off < 256; off <<= 1) {
        int a = (tid >= off) ? sh[tid - off] : 0;
        __syncthreads();
        sh[tid] += a;
        __syncthreads();
    }
    if (i < n) {
        int r = bpre[blockIdx.x] + sh[tid] - v;
        row_ptr[i] = r;
        cursor[i]  = r;
    }
    if (i == 0) row_ptr[n] = n_edges;
}

__global__ void k_scatter(const int* __restrict__ ei, int* __restrict__ cursor,
                          int* __restrict__ elist, const int* __restrict__ flags,
                          int n_edges, int n_nodes) {
    int e = blockIdx.x * blockDim.x + threadIdx.x;
    if (e >= n_edges) return;
    int2 st = edge_st(ei, flags[1], e, n_edges);
    if ((unsigned)st.y < (unsigned)n_nodes && (unsigned)st.x < (unsigned)n_nodes) {
        int pos = atomicAdd(&cursor[st.y], 1);
        elist[pos] = st.x;
    }
}

// ---------- fused 3-iteration routing ----------
// One wave per target. Lane = e8*8 + c: 8 edge slots x 8 capsules.
// Each lane owns capsule c's 16 dims in registers; dot and l2norm are in-lane.
// u lives in registers across all 3 iterations.
__global__ void k_route_f(const int* __restrict__ row_ptr, const int* __restrict__ elist,
                          const float* __restrict__ xc, float* __restrict__ u_out,
                          int n_nodes) {
    int t    = (blockIdx.x * blockDim.x + threadIdx.x) >> 6;
    int lane = threadIdx.x & 63;
    if (t >= n_nodes) return;
    const int e8 = lane >> 3;    // edge slot within chunk
    const int c  = lane & 7;     // capsule

    // xc[t] for this capsule: 16 contiguous floats
    const float* xct = xc + (size_t)t * DF + c * DPC;
    float xt[DPC], u[DPC];
    #pragma unroll
    for (int j = 0; j < DPC; j += 4) {
        float4 v = *reinterpret_cast<const float4*>(xct + j);
        xt[j] = v.x; xt[j+1] = v.y; xt[j+2] = v.z; xt[j+3] = v.w;
    }
    #pragma unroll
    for (int j = 0; j < DPC; ++j) u[j] = xt[j];   // u_0 = xc[t]

    const int beg = row_ptr[t];      // t is wave-uniform -> scalar loads
    const int end = row_ptr[t + 1];

    for (int it = 0; it < 3; ++it) {
        float acc[DPC];
        #pragma unroll
        for (int j = 0; j < DPC; ++j) acc[j] = 0.0f;

        for (int base = beg; base < end; base += 8) {
            int idx = base + e8;
            bool valid = idx < end;
            int s = elist[valid ? idx : beg];
            const float* zs = xc + (size_t)s * DF + c * DPC;
            float z[DPC];
            #pragma unroll
            for (int j = 0; j < DPC; j += 4) {
                float4 v = *reinterpret_cast<const float4*>(zs + j);
                z[j] = v.x; z[j+1] = v.y; z[j+2] = v.z; z[j+3] = v.w;
            }
            // in-lane per-capsule dot
            float p = 0.0f;
            #pragma unroll
            for (int j = 0; j < DPC; ++j) p = fmaf(z[j], u[j], p);
            // softmax over the 8 capsules of this edge (lanes differ in bits 0..2)
            float m = p;
            m = fmaxf(m, __shfl_xor(m, 1));
            m = fmaxf(m, __shfl_xor(m, 2));
            m = fmaxf(m, __shfl_xor(m, 4));
            float ex = __expf(p - m);
            float sd = ex;
            sd += __shfl_xor(sd, 1);
            sd += __shfl_xor(sd, 2);
            sd += __shfl_xor(sd, 4);
            float w = valid ? (ex / sd) : 0.0f;
            #pragma unroll
            for (int j = 0; j < DPC; ++j) acc[j] = fmaf(w, z[j], acc[j]);
        }
        // reduce message across the 8 edge slots (lanes differ in bits 3..5)
        #pragma unroll
        for (int j = 0; j < DPC; ++j) {
            acc[j] += __shfl_xor(acc[j], 8);
            acc[j] += __shfl_xor(acc[j], 16);
            acc[j] += __shfl_xor(acc[j], 32);
        }
        // residual + per-capsule l2norm, all in-lane
        float ss = 0.0f;
        #pragma unroll
        for (int j = 0; j < DPC; ++j) {
            u[j] = acc[j] + xt[j];
            ss = fmaf(u[j], u[j], ss);
        }
        float sc = 1.0f / fmaxf(sqrtf(ss), 1e-12f);
        #pragma unroll
        for (int j = 0; j < DPC; ++j) u[j] *= sc;
    }

    if (e8 == 0) {   // lanes 0..7 cover the full 512B node row
        float* dst = u_out + (size_t)t * DF + c * DPC;
        #pragma unroll
        for (int j = 0; j < DPC; j += 4) {
            *reinterpret_cast<float4*>(dst + j) = make_float4(u[j], u[j+1], u[j+2], u[j+3]);
        }
    }
}

// ---------- fallback (R4-style, safe atomics) if ws is too small ----------
__global__ void k_init_fb(const void* __restrict__ xraw, float* __restrict__ u,
                          float* __restrict__ unew, const int* __restrict__ flags,
                          int n_nodes) {
    int wid  = (blockIdx.x * blockDim.x + threadIdx.x) >> 6;
    int lane = threadIdx.x & 63;
    if (wid >= n_nodes) return;
    float2 v = load_x2(xraw, flags[0], wid, lane);
    float ss = cap_sum(v.x * v.x + v.y * v.y);
    float scale = 1.0f / fmaxf(sqrtf(ss), 1e-12f);
    size_t off = (size_t)wid * DF + (size_t)lane * 2;
    *reinterpret_cast<float2*>(u + off)    = make_float2(v.x * scale, v.y * scale);
    *reinterpret_cast<float2*>(unew + off) = make_float2(0.0f, 0.0f);
}

__global__ void k_edge_fb(const int* __restrict__ ei, const void* __restrict__ xraw,
                          const float* __restrict__ u, float* __restrict__ unew,
                          const int* __restrict__ flags, int n_edges, int n_nodes) {
    int e    = (blockIdx.x * blockDim.x + threadIdx.x) >> 6;
    int lane = threadIdx.x & 63;
    if (e >= n_edges) return;
    int2 st = edge_st(ei, flags[1], e, n_edges);
    if ((unsigned)st.x >= (unsigned)n_nodes || (unsigned)st.y >= (unsigned)n_nodes) return;
    float2 xs = load_x2(xraw, flags[0], st.x, lane);
    float ssz = cap_sum(xs.x * xs.x + xs.y * xs.y);
    float scz = 1.0f / fmaxf(sqrtf(ssz), 1e-12f);
    float zx = xs.x * scz, zy = xs.y * scz;
    size_t toff = (size_t)st.y * DF + (size_t)lane * 2;
    const float2 ut = *reinterpret_cast<const float2*>(u + toff);
    float p = cap_sum(zx * ut.x + zy * ut.y);
    float m = p;
    m = fmaxf(m, __shfl_xor(m, 8));
    m = fmaxf(m, __shfl_xor(m, 16));
    m = fmaxf(m, __shfl_xor(m, 32));
    float ex = __expf(p - m);
    float sd = ex;
    sd += __shfl_xor(sd, 8);
    sd += __shfl_xor(sd, 16);
    sd += __shfl_xor(sd, 32);
    float w = ex / sd;
    atomicAdd(unew + toff,     zx * w);
    atomicAdd(unew + toff + 1, zy * w);
}

__global__ void k_norm_fb(const float* __restrict__ unew_in, const void* __restrict__ xraw,
                          float* __restrict__ u, float* __restrict__ unew_rst,
                          const int* __restrict__ flags, int n_nodes) {
    int wid  = (blockIdx.x * blockDim.x + threadIdx.x) >> 6;
    int lane = threadIdx.x & 63;
    if (wid >= n_nodes) return;
    size_t off = (size_t)wid * DF + (size_t)lane * 2;
    float2 a = *reinterpret_cast<const float2*>(unew_in + off);
    float2 xv = load_x2(xraw, flags[0], wid, lane);
    float ssx = cap_sum(xv.x * xv.x + xv.y * xv.y);
    float scx = 1.0f / fmaxf(sqrtf(ssx), 1e-12f);
    float vx = a.x + xv.x * scx, vy = a.y + xv.y * scx;
    float ss = cap_sum(vx * vx + vy * vy);
    float scale = 1.0f / fmaxf(sqrtf(ss), 1e-12f);
    *reinterpret_cast<float2*>(u + off)        = make_float2(vx * scale, vy * scale);
    *reinterpret_cast<float2*>(unew_rst + off) = make_float2(0.0f, 0.0f);
}

extern "C" void kernel_launch(void* const* d_in, const int* in_sizes, int n_in,
                              void* d_out, int out_size, void* d_ws, size_t ws_size,
                              hipStream_t stream) {
    const void* x  = d_in[0];
    const int*  ei = (const int*)d_in[1];
    const int n_nodes = in_sizes[0] / DF;        // 50000
    const int n_edges = in_sizes[1] / 2;         // 800000

    const size_t NC = (size_t)n_nodes * DF;      // 6.4M floats
    float* u_out = (float*)d_out;                // fp32 output

    // ws layout: xc f32[NC] | row_ptr[n+1] | cursor[n] | elist[E] |
    //            bsum[256] | bpre[256] | flags[2]
    float* xc      = (float*)d_ws;
    int*   row_ptr = (int*)(xc + NC);
    int*   cursor  = row_ptr + (n_nodes + 1);
    int*   elist   = cursor + n_nodes;
    int*   bsum    = elist + n_edges;
    int*   bpre    = bsum + 256;
    int*   flags   = bpre + 256;
    size_t need = (size_t)(flags + 2 - (int*)d_ws) * 4;

    const int tpb = 64 * WPB;                    // 256
    const int nb_nodes = (n_nodes + WPB - 1) / WPB;
    const int nb_flat_nodes = (n_nodes + 255) / 256;   // 196
    const int nb_flat_edges = (n_edges + 255) / 256;   // 3125

    if (ws_size >= need) {
        k_detect<<<1, 256, 0, stream>>>((const unsigned int*)x, (const unsigned int*)ei, flags);
        k_xc<<<nb_nodes, tpb, 0, stream>>>(x, xc, flags, n_nodes);
        k_zero<<<nb_flat_nodes, 256, 0, stream>>>(cursor, n_nodes);
        k_hist<<<nb_flat_edges, 256, 0, stream>>>(ei, cursor, flags, n_edges, n_nodes);
        k_scan_a<<<nb_flat_nodes, 256, 0, stream>>>(cursor, bsum, n_nodes);
        k_scan_b<<<1, 256, 0, stream>>>(bsum, bpre, nb_flat_nodes);
        k_scan_c<<<nb_flat_nodes, 256, 0, stream>>>(cursor, bpre, row_ptr, cursor,
                                                    n_nodes, n_edges);
        k_scatter<<<nb_flat_edges, 256, 0, stream>>>(ei, cursor, elist, flags,
                                                     n_edges, n_nodes);
        k_route_f<<<nb_nodes, tpb, 0, stream>>>(row_ptr, elist, xc, u_out, n_nodes);
    } else {
        float* unew = (float*)d_ws;
        int* flags_fb = (int*)((float*)d_ws + NC);
        k_detect<<<1, 256, 0, stream>>>((const unsigned int*)x, (const unsigned int*)ei, flags_fb);
        k_init_fb<<<nb_nodes, tpb, 0, stream>>>(x, u_out, unew, flags_fb, n_nodes);
        for (int it = 0; it < 3; ++it) {
            k_edge_fb<<<(n_edges + WPB - 1) / WPB, tpb, 0, stream>>>(
                ei, x, u_out, unew, flags_fb, n_edges, n_nodes);
            k_norm_fb<<<nb_nodes, tpb, 0, stream>>>(unew, x, u_out, unew, flags_fb, n_nodes);
        }
    }
}